// Round 2
// baseline (19094.983 us; speedup 1.0000x reference)
//
#include <hip/hip_runtime.h>
#include <hip/hip_bf16.h>

typedef _Float16 f16_t;
using f16x8  = __attribute__((ext_vector_type(8))) _Float16;
using f32x4  = __attribute__((ext_vector_type(4))) float;
using f32x16 = __attribute__((ext_vector_type(16))) float;
using u64    = unsigned long long;
using u64x2  = __attribute__((ext_vector_type(2))) unsigned long long;

#define L_DIM 512
#define B_DIM 64
#define C_DIM 512
#define H_DIM 1024
#define MROWS (L_DIM * B_DIM) /* 32768 */

// ---------------- f32 -> f16 convert ----------------
__global__ void cvt_kernel(const float* __restrict__ src, f16_t* __restrict__ dst, int n8) {
  int i = blockIdx.x * blockDim.x + threadIdx.x;
  if (i >= n8) return;
  const float4* s4 = reinterpret_cast<const float4*>(src) + (size_t)i * 2;
  float4 a = s4[0], b = s4[1];
  f16x8 o;
  o[0] = (f16_t)a.x; o[1] = (f16_t)a.y; o[2] = (f16_t)a.z; o[3] = (f16_t)a.w;
  o[4] = (f16_t)b.x; o[5] = (f16_t)b.y; o[6] = (f16_t)b.z; o[7] = (f16_t)b.w;
  reinterpret_cast<f16x8*>(dst)[i] = o;
}

// ---------------- async global->LDS 16B ----------------
__device__ inline void gload_lds16(const void* g, void* l) {
  __builtin_amdgcn_global_load_lds(
      (const __attribute__((address_space(1))) unsigned int*)g,
      (__attribute__((address_space(3))) unsigned int*)l, 16, 0, 0);
}

// ---------------- bt-GEMM: C[M,N] = A[M,K] @ B[N,K]^T + bias ----------------
#define TM 128
#define TN 128
#define BKK 64
__global__ __launch_bounds__(256) void gemm_bt_bias(
    const f16_t* __restrict__ A, const f16_t* __restrict__ B,
    const float* __restrict__ bias, float* __restrict__ C,
    int M, int N, int K) {
  __shared__ f16_t As[TM * BKK];
  __shared__ f16_t Bs[TN * BKK];
  const int tid = threadIdx.x;
  const int w = tid >> 6, l = tid & 63;
  const int nbn = N / TN;
  const int bm = blockIdx.x / nbn, bn = blockIdx.x % nbn;
  const int m0 = bm * TM, n0 = bn * TN;
  const int wr = w >> 1, wc = w & 1;
  const int lr = l & 15;
  const int lk = (l >> 4) * 8;
  f32x4 acc[4][4] = {};

  for (int kt = 0; kt < K; kt += BKK) {
#pragma unroll
    for (int r = 0; r < 4; ++r) {
      int p8 = r * 256 + tid;
      int row = p8 >> 3, col = (p8 & 7) * 8;
      gload_lds16(A + (size_t)(m0 + row) * K + kt + col, &As[(size_t)(r * 256 + w * 64) * 8]);
    }
#pragma unroll
    for (int r = 0; r < 4; ++r) {
      int p8 = r * 256 + tid;
      int row = p8 >> 3, col = (p8 & 7) * 8;
      gload_lds16(B + (size_t)(n0 + row) * K + kt + col, &Bs[(size_t)(r * 256 + w * 64) * 8]);
    }
    __syncthreads();
#pragma unroll
    for (int kk = 0; kk < 2; ++kk) {
      f16x8 af[4], bfr[4];
#pragma unroll
      for (int i = 0; i < 4; ++i)
        af[i] = *reinterpret_cast<const f16x8*>(&As[(wr * 64 + i * 16 + lr) * BKK + kk * 32 + lk]);
#pragma unroll
      for (int j = 0; j < 4; ++j)
        bfr[j] = *reinterpret_cast<const f16x8*>(&Bs[(wc * 64 + j * 16 + lr) * BKK + kk * 32 + lk]);
#pragma unroll
      for (int i = 0; i < 4; ++i)
#pragma unroll
        for (int j = 0; j < 4; ++j)
          acc[i][j] = __builtin_amdgcn_mfma_f32_16x16x32_f16(af[i], bfr[j], acc[i][j], 0, 0, 0);
    }
    __syncthreads();
  }
  const int crow = (l >> 4) * 4, ccol = l & 15;
#pragma unroll
  for (int j = 0; j < 4; ++j) {
    int col = n0 + wc * 64 + j * 16 + ccol;
    float bv = bias[col];
#pragma unroll
    for (int i = 0; i < 4; ++i) {
      int rowb = m0 + wr * 64 + i * 16 + crow;
#pragma unroll
      for (int r = 0; r < 4; ++r)
        C[(size_t)(rowb + r) * N + col] = acc[i][j][r] + bv;
    }
  }
}

// ---------------- persistent-scan inter-block barrier ----------------
__device__ inline void scan_barrier(unsigned* flags, int g, unsigned target, int tid) {
  __syncthreads();  // drains vmcnt -> prior agent-scope stores complete at coherence point
  if (tid < 64) {
    if (tid == 0)
      __hip_atomic_store(&flags[g], target, __ATOMIC_RELAXED, __HIP_MEMORY_SCOPE_AGENT);
    int src = tid & 15;
    while (true) {
      unsigned v = __hip_atomic_load(&flags[src], __ATOMIC_RELAXED, __HIP_MEMORY_SCOPE_AGENT);
      if (__all((int)(v >= target))) break;
    }
  }
  __syncthreads();
}

// ---------------- recurrent scan: h = tanh(xp_t + h @ W^T) ----------------
// 16 blocks x 256 threads. Block g owns output cols [g*64, g*64+64).
// W slice (64 rows x 1024) resident in LDS (XOR swizzled). h ping-pongs in
// global ws as f16, cross-XCD coherent via agent-scope atomics.
__global__ __launch_bounds__(256, 1) void rnn_scan(
    const float* __restrict__ xp,     // [512][64][1024] f32
    const f16_t* __restrict__ Wr,     // [1024][1024] f16 (W_hh)
    const float* __restrict__ h0in,   // [64][1024] f32 initial state
    f16_t* __restrict__ hbuf,         // 2 x 64*1024 f16 ping-pong
    unsigned* __restrict__ flags,     // 16 flags
    f16_t* __restrict__ out_h,        // [512][64][1024] f16 or null
    float* __restrict__ out_f,        // [512][64][1024] f32 or null
    float* __restrict__ state_out) {  // [64][1024] f32 final h
  extern __shared__ char smem[];      // 64 * 2048 B = 128 KiB
  const int tid = threadIdx.x, g = blockIdx.x;
  const int w = tid >> 6, l = tid & 63;
  const int n0 = g * 64;
  const int wr = w >> 1, wc = w & 1;
  const int la = l & 31, lb = l >> 5;

  // stage W slice (rows n0..n0+63, all K) into LDS with XOR swizzle on 16B granules
  for (int i = 0; i < 32; ++i) {
    int g8 = i * 256 + tid;           // [0, 8192)
    int row = g8 >> 7, cb = g8 & 127;
    f16x8 v = *reinterpret_cast<const f16x8*>(Wr + (size_t)(n0 + row) * H_DIM + cb * 8);
    *reinterpret_cast<f16x8*>(smem + row * 2048 + ((cb ^ (row & 31)) << 4)) = v;
  }
  // init ping h from input state (this block's column slice), agent-scope
  {
    unsigned* hp = reinterpret_cast<unsigned*>(hbuf);
    for (int i = 0; i < 8; ++i) {
      int idx = i * 256 + tid;        // [0, 2048) f16-pairs
      int row = idx >> 5, cp = idx & 31;
      int col = n0 + cp * 2;
      float f0 = h0in[row * H_DIM + col];
      float f1 = h0in[row * H_DIM + col + 1];
      unsigned short u0 = __builtin_bit_cast(unsigned short, (f16_t)f0);
      unsigned short u1 = __builtin_bit_cast(unsigned short, (f16_t)f1);
      unsigned pk = (unsigned)u0 | ((unsigned)u1 << 16);
      __hip_atomic_store(&hp[(row * H_DIM + col) >> 1], pk, __ATOMIC_RELAXED, __HIP_MEMORY_SCOPE_AGENT);
    }
  }
  scan_barrier(flags, g, 1u, tid);

  const int arow = wr * 32 + la;        // h row this lane reads (A operand)
  const int colg = n0 + wc * 32 + la;   // output col this lane owns
  const int rwrow = wc * 32 + la;       // W-slice row for B operand
  const char* smem_wrow = smem + rwrow * 2048;
  const int rx = rwrow & 31;

  for (int t = 0; t < 512; ++t) {
    const char* hs = reinterpret_cast<const char*>(hbuf + (size_t)(t & 1) * (B_DIM * H_DIM));
    unsigned short* hd = reinterpret_cast<unsigned short*>(hbuf + (size_t)((t + 1) & 1) * (B_DIM * H_DIM));
    const char* hrow = hs + ((size_t)arow * H_DIM + lb * 8) * 2;

    // prefetch xp values for the epilogue (independent of h)
    float xv[16];
#pragma unroll
    for (int r = 0; r < 16; ++r) {
      int row = wr * 32 + (r & 3) + 8 * (r >> 2) + 4 * lb;
      xv[r] = xp[(size_t)t * (B_DIM * H_DIM) + row * H_DIM + colg];
    }

    f32x16 acc = {};
    u64 p0[2][16], p1[2][16];
#pragma unroll
    for (int i = 0; i < 16; ++i) {
      p0[0][i] = __hip_atomic_load((const u64*)(hrow + i * 32), __ATOMIC_RELAXED, __HIP_MEMORY_SCOPE_AGENT);
      p1[0][i] = __hip_atomic_load((const u64*)(hrow + i * 32 + 8), __ATOMIC_RELAXED, __HIP_MEMORY_SCOPE_AGENT);
    }
#pragma unroll
    for (int kb = 0; kb < 4; ++kb) {
      const int cur = kb & 1, nxt = cur ^ 1;
      if (kb < 3) {
#pragma unroll
        for (int i = 0; i < 16; ++i) {
          p0[nxt][i] = __hip_atomic_load((const u64*)(hrow + (kb * 16 + 16 + i) * 32), __ATOMIC_RELAXED, __HIP_MEMORY_SCOPE_AGENT);
          p1[nxt][i] = __hip_atomic_load((const u64*)(hrow + (kb * 16 + 16 + i) * 32 + 8), __ATOMIC_RELAXED, __HIP_MEMORY_SCOPE_AGENT);
        }
      }
#pragma unroll
      for (int i = 0; i < 16; ++i) {
        int kc = kb * 16 + i;
        int cb = (kc * 2 + lb) ^ rx;
        f16x8 bfr = *reinterpret_cast<const f16x8*>(smem_wrow + (cb << 4));
        u64x2 aa; aa[0] = p0[cur][i]; aa[1] = p1[cur][i];
        f16x8 af = __builtin_bit_cast(f16x8, aa);
        acc = __builtin_amdgcn_mfma_f32_32x32x16_f16(af, bfr, acc, 0, 0, 0);
      }
    }

    const bool wlast = (t == 511);
#pragma unroll
    for (int r = 0; r < 16; ++r) {
      int row = wr * 32 + (r & 3) + 8 * (r >> 2) + 4 * lb;
      float z = acc[r] + xv[r];
      z = fminf(fmaxf(z, -15.f), 15.f);
      float e = __expf(2.f * z);
      float h = 1.f - __fdividef(2.f, e + 1.f);
      unsigned short hb = __builtin_bit_cast(unsigned short, (f16_t)h);
      __hip_atomic_store(&hd[row * H_DIM + colg], hb, __ATOMIC_RELAXED, __HIP_MEMORY_SCOPE_AGENT);
      if (out_h) out_h[(size_t)t * (B_DIM * H_DIM) + row * H_DIM + colg] = __builtin_bit_cast(f16_t, hb);
      if (out_f) out_f[(size_t)t * (B_DIM * H_DIM) + row * H_DIM + colg] = h;
      if (wlast) state_out[row * H_DIM + colg] = h;
    }
    if (!wlast) scan_barrier(flags, g, (unsigned)(t + 2), tid);
  }
}

extern "C" void kernel_launch(void* const* d_in, const int* in_sizes, int n_in,
                              void* d_out, int out_size, void* d_ws, size_t ws_size,
                              hipStream_t stream) {
  const float* x     = (const float*)d_in[0];
  const float* state = (const float*)d_in[1];
  const float* Wih0  = (const float*)d_in[2];
  const float* Whh0  = (const float*)d_in[3];
  const float* b0    = (const float*)d_in[4];
  const float* Wih1  = (const float*)d_in[5];
  const float* Whh1  = (const float*)d_in[6];
  const float* b1    = (const float*)d_in[7];
  float* out = (float*)d_out;

  char* ws = (char*)d_ws;
  unsigned* flags = (unsigned*)(ws + 0);               //   1 KiB (flags x2 sets)
  f16_t* hbuf     = (f16_t*)(ws + 1024);               // 256 KiB ping-pong h
  f16_t* Wih0h    = (f16_t*)(ws + 263168);
  f16_t* Whh0h    = (f16_t*)(ws + 1311744);
  f16_t* Wih1h    = (f16_t*)(ws + 3408896);
  f16_t* Whh1h    = (f16_t*)(ws + 5506048);
  f16_t* xh       = (f16_t*)(ws + 7603200);            //  32 MiB x f16
  f16_t* out0     = (f16_t*)(ws + 41157632);           //  64 MiB layer0 outputs f16
  float* xp       = (float*)(ws + 108266496);          // 128 MiB input projections f32

  hipMemsetAsync(ws, 0, 1024, stream);
  cvt_kernel<<<8192, 256, 0, stream>>>(x,    xh,    16777216 / 8);
  cvt_kernel<<<256,  256, 0, stream>>>(Wih0, Wih0h,   524288 / 8);
  cvt_kernel<<<512,  256, 0, stream>>>(Whh0, Whh0h,  1048576 / 8);
  cvt_kernel<<<512,  256, 0, stream>>>(Wih1, Wih1h,  1048576 / 8);
  cvt_kernel<<<512,  256, 0, stream>>>(Whh1, Whh1h,  1048576 / 8);

  // layer 0 input projection: [32768,512] @ [1024,512]^T
  gemm_bt_bias<<<dim3((MROWS / TM) * (H_DIM / TN)), 256, 0, stream>>>(
      xh, Wih0h, b0, xp, MROWS, H_DIM, C_DIM);

  (void)hipFuncSetAttribute((const void*)rnn_scan,
                            hipFuncAttributeMaxDynamicSharedMemorySize, 131072);
  float* state_out = out + (size_t)L_DIM * B_DIM * H_DIM;  // 33554432
  rnn_scan<<<16, 256, 131072, stream>>>(xp, Whh0h, state, hbuf, flags,
                                        out0, nullptr, state_out);
  // layer 1 input projection: [32768,1024] @ [1024,1024]^T
  gemm_bt_bias<<<dim3((MROWS / TM) * (H_DIM / TN)), 256, 0, stream>>>(
      out0, Wih1h, b1, xp, MROWS, H_DIM, H_DIM);
  rnn_scan<<<16, 256, 131072, stream>>>(xp, Whh1h, state + B_DIM * H_DIM, hbuf, flags + 16,
                                        nullptr, out, state_out + B_DIM * H_DIM);
}